// Round 3
// baseline (43383.310 us; speedup 1.0000x reference)
//
#include <hip/hip_runtime.h>
#include <math.h>

#define BB_   64
#define TT_   256
#define DIN_  256
#define HH_   512
#define NMEM_ 128
#define WWID_ 64
#define RR_   4
#define DOUT_ 256
#define CTRL_ 512
#define EPSV  1e-8f
#define NBLK  256
#define NTHR  256

__device__ __forceinline__ float sigm(float x){ return 1.f/(1.f+expf(-x)); }
__device__ __forceinline__ float softp(float x){ return (x>20.f)? x : log1pf(expf(x)); }
__device__ __forceinline__ float wredsum(float v){
  #pragma unroll
  for (int o=32;o>0;o>>=1) v += __shfl_xor(v,o,64);
  return v;
}
__device__ __forceinline__ float wredmax(float v){
  #pragma unroll
  for (int o=32;o>0;o>>=1) v = fmaxf(v, __shfl_xor(v,o,64));
  return v;
}

// ---- custom grid barrier: sense-reversing, agent-scope, self-resetting ----
__device__ __forceinline__ void gridbar(unsigned* cnt, unsigned* epoch)
{
  __syncthreads();               // all block stores issued & waited (vmcnt)
  if (threadIdx.x == 0) {
    __threadfence();             // agent acq_rel: L2 writeback + L1 inv
    unsigned e = __hip_atomic_load(epoch, __ATOMIC_RELAXED, __HIP_MEMORY_SCOPE_AGENT);
    unsigned a = __hip_atomic_fetch_add(cnt, 1u, __ATOMIC_ACQ_REL, __HIP_MEMORY_SCOPE_AGENT);
    if (a == (unsigned)(NBLK - 1)) {
      __hip_atomic_store(cnt, 0u, __ATOMIC_RELAXED, __HIP_MEMORY_SCOPE_AGENT);
      __hip_atomic_store(epoch, e + 1u, __ATOMIC_RELEASE, __HIP_MEMORY_SCOPE_AGENT);
    } else {
      while (__hip_atomic_load(epoch, __ATOMIC_ACQUIRE, __HIP_MEMORY_SCOPE_AGENT) == e)
        __builtin_amdgcn_s_sleep(2);
    }
    __threadfence();             // make remote data visible to this CU
  }
  __syncthreads();
}

__global__ void k_initbar(unsigned* bar){
  if (threadIdx.x == 0) { bar[0] = 0u; bar[32] = 0u; }
}

struct Params {
  const float *x, *Wih, *Whh, *bih, *bhh, *Wint, *bint, *Wout, *bout;
  float *out;
  float *xbuf;   // 2 * 16384  (x_t packed [k/4][b][4])
  float *hp;     // 2 * 32768  (h packed)
  float *cT;     // 32768      ([j][b])
  float *rvp;    // 16384      (rv packed)
  float *mem;    // 524288     ([b][n][w])
  float *ifc;    // 456*64     ([o][b])
  unsigned *bar; // cnt at [0], epoch at [32]
};

union SM {
  float redA[4][8][64];
  float redB[4][2][64];
  float redO[4][4][64];
  struct {
    float memS[NMEM_][WWID_];
    float aS[NMEM_];
    float rS[RR_][NMEM_];
    float wwS[NMEM_];
  } c;
};

__launch_bounds__(NTHR)
__global__ void k_persist(Params p)
{
  __shared__ SM sm;

  const int bi  = blockIdx.x;
  const int tid = threadIdx.x;
  const int b   = tid & 63;
  const int wv  = tid >> 6;

  // ---- init: zero recurrent state; transpose x_0 into xbuf[0] ----
  {
    float4* z = (float4*)p.hp;   // hp,cT,rvp,mem contiguous in ws
    const int nz4 = (2*HH_*64 + HH_*64 + RR_*WWID_*64 + BB_*NMEM_*WWID_) >> 2;
    for (int i = bi*NTHR + tid; i < nz4; i += NBLK*NTHR)
      z[i] = make_float4(0.f, 0.f, 0.f, 0.f);
    if (bi >= 240) {
      const int g  = (bi - 240)*NTHR + tid;   // 0..4095
      const int bb = g >> 6, kq = g & 63;
      float4 v = *(const float4*)(p.x + (size_t)bb*(TT_*DIN_) + 4*kq);
      *(float4*)(p.xbuf + kq*256 + bb*4) = v;
    }
  }
  gridbar(p.bar, p.bar + 32);

  for (int t = 0; t < TT_; ++t) {
    const int cur = t & 1, nxt = cur ^ 1;
    const float* hR = p.hp + cur*32768;
    float*       hW = p.hp + nxt*32768;

    // ================= Phase A: gates GEMM + LSTM =================
    {
      const int j0 = bi*2;
      const float4* ap;
      if      (wv == 0) ap = (const float4*)(p.xbuf + cur*16384);
      else if (wv == 1) ap = (const float4*)p.rvp;
      else if (wv == 2) ap = (const float4*)hR;
      else              ap = (const float4*)(hR + 16384);
      const int    koff = (wv & 1) * 256;
      const float* Wsrc = (wv < 2) ? p.Wih : p.Whh;

      const float* wb[8];
      #pragma unroll
      for (int g = 0; g < 4; ++g)
        #pragma unroll
        for (int jj = 0; jj < 2; ++jj)
          wb[g*2+jj] = Wsrc + (size_t)(g*HH_ + j0 + jj)*CTRL_ + koff;

      float acc[8];
      #pragma unroll
      for (int r = 0; r < 8; ++r) acc[r] = 0.f;

      #pragma unroll 4
      for (int kk = 0; kk < 64; ++kk) {
        float4 a = ap[kk*64 + b];
        #pragma unroll
        for (int r = 0; r < 8; ++r) {
          float4 w = *(const float4*)(wb[r] + kk*4);
          acc[r] += w.x*a.x + w.y*a.y + w.z*a.z + w.w*a.w;
        }
      }
      #pragma unroll
      for (int r = 0; r < 8; ++r) sm.redA[wv][r][b] = acc[r];
      __syncthreads();

      if (tid < 128) {
        const int jj = tid >> 6;
        const int j  = j0 + jj;
        float gs[4];
        #pragma unroll
        for (int g = 0; g < 4; ++g) {
          float s = sm.redA[0][g*2+jj][b] + sm.redA[1][g*2+jj][b]
                  + sm.redA[2][g*2+jj][b] + sm.redA[3][g*2+jj][b];
          gs[g] = s + p.bih[g*HH_ + j] + p.bhh[g*HH_ + j];
        }
        float c  = p.cT[j*64 + b];
        float cn = sigm(gs[1])*c + sigm(gs[0])*tanhf(gs[2]);
        float hn = sigm(gs[3])*tanhf(cn);
        p.cT[j*64 + b] = cn;
        hW[(j>>2)*256 + b*4 + (j&3)] = hn;
      }
    }
    gridbar(p.bar, p.bar + 32);

    // ============ Phase B: iface GEMM (+ transpose x_{t+1}) ============
    {
      if (bi < 227) {
        const int o0 = bi*2;
        const float4* hp4 = (const float4*)hW;
        const float* w0 = p.Wint + (size_t)o0*HH_ + wv*128;
        const float* w1 = (o0+1 < 453) ? (p.Wint + (size_t)(o0+1)*HH_ + wv*128) : w0;
        float a0 = 0.f, a1 = 0.f;
        #pragma unroll 4
        for (int kk = 0; kk < 32; ++kk) {
          float4 a = hp4[(wv*32 + kk)*64 + b];
          float4 u = *(const float4*)(w0 + kk*4);
          float4 v = *(const float4*)(w1 + kk*4);
          a0 += u.x*a.x + u.y*a.y + u.z*a.z + u.w*a.w;
          a1 += v.x*a.x + v.y*a.y + v.z*a.z + v.w*a.w;
        }
        sm.redB[wv][0][b] = a0;
        sm.redB[wv][1][b] = a1;
      }
      if (bi >= 240 && t+1 < TT_) {
        const int g  = (bi - 240)*NTHR + tid;
        const int bb = g >> 6, kq = g & 63;
        float4 v = *(const float4*)(p.x + (size_t)bb*(TT_*DIN_) + (size_t)(t+1)*DIN_ + 4*kq);
        *(float4*)(p.xbuf + nxt*16384 + kq*256 + bb*4) = v;
      }
      __syncthreads();
      if (bi < 227 && tid < 128) {
        const int jj = tid >> 6;
        const int o  = bi*2 + jj;
        if (o < 453) {
          float s = sm.redB[0][jj][b] + sm.redB[1][jj][b]
                  + sm.redB[2][jj][b] + sm.redB[3][jj][b];
          p.ifc[o*64 + b] = s + p.bint[o];
        }
      }
    }
    gridbar(p.bar, p.bar + 32);

    // ================= Phase C: content addressing =================
    {
      if (bi < BB_) {
        const int bb   = bi;
        const int lane = b;
        float* gm = p.mem + (size_t)bb*NMEM_*WWID_;
        for (int i = tid; i < NMEM_*WWID_; i += NTHR)
          sm.c.memS[i>>6][i&63] = gm[i];

        const float wkey = p.ifc[(260+lane)*64 + bb];
        const float er   = sigm(p.ifc[(325+lane)*64 + bb]);
        const float wvec = p.ifc[(389+lane)*64 + bb];
        float rkey[RR_], rstr[RR_], nkr[RR_];
        #pragma unroll
        for (int r = 0; r < RR_; ++r) rkey[r] = p.ifc[(r*64+lane)*64 + bb];
        const float wstr = softp(p.ifc[324*64 + bb]) + 1.f;
        #pragma unroll
        for (int r = 0; r < RR_; ++r) rstr[r] = softp(p.ifc[(256+r)*64 + bb]) + 1.f;

        const float nkw = fmaxf(sqrtf(wredsum(wkey*wkey)), EPSV);
        #pragma unroll
        for (int r = 0; r < RR_; ++r) nkr[r] = fmaxf(sqrtf(wredsum(rkey[r]*rkey[r])), EPSV);
        __syncthreads();

        for (int n = wv; n < NMEM_; n += 4) {
          float m = sm.c.memS[n][lane];
          float d = wredsum(wkey*m);
          float q = wredsum(m*m);
          if (lane == 0)
            sm.c.aS[n] = wstr * d / (nkw * fmaxf(sqrtf(q), EPSV));
        }
        __syncthreads();

        if (wv == 0) {
          float v0 = sm.c.aS[lane], v1 = sm.c.aS[lane+64];
          float mx = wredmax(fmaxf(v0, v1));
          float e0 = expf(v0-mx), e1 = expf(v1-mx);
          float s  = wredsum(e0+e1);
          sm.c.wwS[lane]    = e0/s;
          sm.c.wwS[lane+64] = e1/s;
        }
        __syncthreads();

        for (int n = wv; n < NMEM_; n += 4) {
          float w  = sm.c.wwS[n];
          float m  = sm.c.memS[n][lane];
          float mn = m*(1.f - w*er) + w*wvec;
          sm.c.memS[n][lane] = mn;
          float nm = fmaxf(sqrtf(wredsum(mn*mn)), EPSV);
          #pragma unroll
          for (int r = 0; r < RR_; ++r) {
            float d = wredsum(rkey[r]*mn);
            if (lane == 0) sm.c.rS[r][n] = rstr[r]*d/(nkr[r]*nm);
          }
        }
        __syncthreads();

        {
          float v0 = sm.c.rS[wv][lane], v1 = sm.c.rS[wv][lane+64];
          float mx = wredmax(fmaxf(v0, v1));
          float e0 = expf(v0-mx), e1 = expf(v1-mx);
          float s  = wredsum(e0+e1);
          sm.c.rS[wv][lane]    = e0/s;
          sm.c.rS[wv][lane+64] = e1/s;
        }
        __syncthreads();

        {
          float acc = 0.f;
          for (int n = 0; n < NMEM_; ++n)
            acc += sm.c.rS[wv][n]*sm.c.memS[n][lane];
          const int k = wv*64 + lane;
          p.rvp[(k>>2)*256 + bb*4 + (k&3)] = acc;
        }
        __syncthreads();
        for (int i = tid; i < NMEM_*WWID_; i += NTHR)
          gm[i] = sm.c.memS[i>>6][i&63];
      }
    }
    gridbar(p.bar, p.bar + 32);
  }

  // ================= Output projection (last step only) =================
  if (bi < 64) {
    const float4* hp4 = (const float4*)p.hp;      // TT_ even -> final h in hp[0]
    const float4* rp4 = (const float4*)p.rvp;
    const int o0 = bi*4;
    float acc[4] = {0.f, 0.f, 0.f, 0.f};
    #pragma unroll 4
    for (int kk = 0; kk < 48; ++kk) {
      const int k = wv*192 + kk*4;
      float4 a = (k < 512) ? hp4[(k>>2)*64 + b] : rp4[((k-512)>>2)*64 + b];
      #pragma unroll
      for (int r = 0; r < 4; ++r) {
        float4 w = *(const float4*)(p.Wout + (size_t)(o0+r)*(HH_ + RR_*WWID_) + k);
        acc[r] += w.x*a.x + w.y*a.y + w.z*a.z + w.w*a.w;
      }
    }
    #pragma unroll
    for (int r = 0; r < 4; ++r) sm.redO[wv][r][b] = acc[r];
    __syncthreads();
    if (tid < 64) {
      float4 o4;
      float* po = (float*)&o4;
      #pragma unroll
      for (int r = 0; r < 4; ++r)
        po[r] = sm.redO[0][r][b] + sm.redO[1][r][b] + sm.redO[2][r][b]
              + sm.redO[3][r][b] + p.bout[o0+r];
      *(float4*)(p.out + (size_t)b*DOUT_ + o0) = o4;
    }
  }
}

extern "C" void kernel_launch(void* const* d_in, const int* in_sizes, int n_in,
                              void* d_out, int out_size, void* d_ws, size_t ws_size,
                              hipStream_t stream)
{
  Params prm;
  prm.x    = (const float*)d_in[0];
  prm.Wih  = (const float*)d_in[1];
  prm.Whh  = (const float*)d_in[2];
  prm.bih  = (const float*)d_in[3];
  prm.bhh  = (const float*)d_in[4];
  prm.Wint = (const float*)d_in[5];
  prm.bint = (const float*)d_in[6];
  prm.Wout = (const float*)d_in[7];
  prm.bout = (const float*)d_in[8];
  prm.out  = (float*)d_out;

  float* ws = (float*)d_ws;
  size_t off = 0;
  prm.xbuf = ws + off; off += 2*16384;
  prm.hp   = ws + off; off += 2*32768;     // hp..mem must stay contiguous (zero span)
  prm.cT   = ws + off; off += 32768;
  prm.rvp  = ws + off; off += 16384;
  prm.mem  = ws + off; off += (size_t)BB_*NMEM_*WWID_;
  prm.ifc  = ws + off; off += 456*64;
  prm.bar  = (unsigned*)(ws + off); off += 64;

  k_initbar<<<1, 64, 0, stream>>>(prm.bar);
  k_persist<<<NBLK, NTHR, 0, stream>>>(prm);
}

// Round 4
// 25717.572 us; speedup vs baseline: 1.6869x; 1.6869x over previous
//
#include <hip/hip_runtime.h>
#include <math.h>

#define BB_   64
#define TT_   256
#define DIN_  256
#define HH_   512
#define NMEM_ 128
#define WWID_ 64
#define RR_   4
#define DOUT_ 256
#define CTRL_ 512
#define EPSV  1e-8f
#define NBLK  256
#define NTHR  256

__device__ __forceinline__ float sigm(float x){ return 1.f/(1.f+expf(-x)); }
__device__ __forceinline__ float softp(float x){ return (x>20.f)? x : log1pf(expf(x)); }
__device__ __forceinline__ float wredsum(float v){
  #pragma unroll
  for (int o=32;o>0;o>>=1) v += __shfl_xor(v,o,64);
  return v;
}
__device__ __forceinline__ float wredmax(float v){
  #pragma unroll
  for (int o=32;o>0;o>>=1) v = fmaxf(v, __shfl_xor(v,o,64));
  return v;
}

// ---- grid barrier: monotonic epoch, relaxed polling, scoped fences ----
// k: this barrier's global index (same sequence in every block).
// E: number of arriving blocks. arrive: did this block write global data?
__device__ __forceinline__ void gridbar(unsigned* cnt, unsigned* epoch,
                                        unsigned k, unsigned E, bool arrive)
{
  __syncthreads();                       // drains this block's vmcnt/lgkmcnt
  if (threadIdx.x == 0) {
    bool released = false;
    if (arrive) {
      __builtin_amdgcn_fence(__ATOMIC_RELEASE, "agent");   // L2 writeback once
      unsigned a = __hip_atomic_fetch_add(cnt, 1u, __ATOMIC_RELAXED,
                                          __HIP_MEMORY_SCOPE_AGENT);
      if (a == E - 1u) {
        __hip_atomic_store(cnt, 0u, __ATOMIC_RELAXED, __HIP_MEMORY_SCOPE_AGENT);
        __hip_atomic_store(epoch, k, __ATOMIC_RELEASE, __HIP_MEMORY_SCOPE_AGENT);
        released = true;
      }
    }
    if (!released) {
      while (__hip_atomic_load(epoch, __ATOMIC_RELAXED,
                               __HIP_MEMORY_SCOPE_AGENT) < k)
        __builtin_amdgcn_s_sleep(2);
    }
    __builtin_amdgcn_fence(__ATOMIC_ACQUIRE, "agent");     // invalidate once
  }
  __syncthreads();
}

__global__ void k_initbar(unsigned* bar){
  if (threadIdx.x == 0) { bar[0] = 0u; bar[32] = 0u; }
}

struct Params {
  const float *x, *Wih, *Whh, *bih, *bhh, *Wint, *bint, *Wout, *bout;
  float *out;
  float *xbuf;   // 2 * 16384  (x_t packed [k/4][b][4])
  float *hp;     // 2 * 32768  (h packed)
  float *rvp;    // 16384      (rv packed)
  float *ifc;    // 456*64     ([o][b])
  unsigned *bar; // cnt at [0], epoch at [32]
};

union SM {
  float redA[4][8][64];
  float redB[4][2][64];
  float redO[4][4][64];
  struct {
    float aS[NMEM_];
    float rS[RR_][NMEM_];
    float wwS[NMEM_];
  } c;
};

__launch_bounds__(NTHR)
__global__ void k_persist(Params p)
{
  __shared__ SM sm;
  __shared__ float memS[NMEM_][WWID_];   // persistent DNC memory (block-private)

  const int bi  = blockIdx.x;
  const int tid = threadIdx.x;
  const int b   = tid & 63;
  const int wv  = tid >> 6;

  unsigned* cnt   = p.bar;
  unsigned* epoch = p.bar + 32;

  float c_reg = 0.f;                     // LSTM cell state for (j=bi*2+(tid>>6), b), tid<128

  // ---- init: zero h/rv, zero LDS memory, transpose x_0 ----
  {
    float4* z = (float4*)p.hp;           // hp, rvp contiguous in ws
    const int nz4 = (2*HH_*64 + RR_*WWID_*64) >> 2;
    for (int i = bi*NTHR + tid; i < nz4; i += NBLK*NTHR)
      z[i] = make_float4(0.f, 0.f, 0.f, 0.f);
    for (int i = tid; i < NMEM_*WWID_; i += NTHR)
      ((float*)memS)[i] = 0.f;
    if (bi >= 240) {
      const int g  = (bi - 240)*NTHR + tid;   // 0..4095
      const int bb = g >> 6, kq = g & 63;
      float4 v = *(const float4*)(p.x + (size_t)bb*(TT_*DIN_) + 4*kq);
      *(float4*)(p.xbuf + kq*256 + bb*4) = v;
    }
  }
  unsigned bk = 1;
  gridbar(cnt, epoch, bk, NBLK, true);

  for (int t = 0; t < TT_; ++t) {
    const int cur = t & 1, nxt = cur ^ 1;
    const float* hR = p.hp + cur*32768;
    float*       hW = p.hp + nxt*32768;

    // ================= Phase A: gates GEMM + LSTM =================
    {
      const int j0 = bi*2;
      const float4* ap;
      if      (wv == 0) ap = (const float4*)(p.xbuf + cur*16384);
      else if (wv == 1) ap = (const float4*)p.rvp;
      else if (wv == 2) ap = (const float4*)hR;
      else              ap = (const float4*)(hR + 16384);
      const int    koff = (wv & 1) * 256;
      const float* Wsrc = (wv < 2) ? p.Wih : p.Whh;

      const float* wb[8];
      #pragma unroll
      for (int g = 0; g < 4; ++g)
        #pragma unroll
        for (int jj = 0; jj < 2; ++jj)
          wb[g*2+jj] = Wsrc + (size_t)(g*HH_ + j0 + jj)*CTRL_ + koff;

      float acc[8];
      #pragma unroll
      for (int r = 0; r < 8; ++r) acc[r] = 0.f;

      #pragma unroll 4
      for (int kk = 0; kk < 64; ++kk) {
        float4 a = ap[kk*64 + b];
        #pragma unroll
        for (int r = 0; r < 8; ++r) {
          float4 w = *(const float4*)(wb[r] + kk*4);
          acc[r] += w.x*a.x + w.y*a.y + w.z*a.z + w.w*a.w;
        }
      }
      #pragma unroll
      for (int r = 0; r < 8; ++r) sm.redA[wv][r][b] = acc[r];
      __syncthreads();

      if (tid < 128) {
        const int jj = tid >> 6;
        const int j  = j0 + jj;
        float gs[4];
        #pragma unroll
        for (int g = 0; g < 4; ++g) {
          float s = sm.redA[0][g*2+jj][b] + sm.redA[1][g*2+jj][b]
                  + sm.redA[2][g*2+jj][b] + sm.redA[3][g*2+jj][b];
          gs[g] = s + p.bih[g*HH_ + j] + p.bhh[g*HH_ + j];
        }
        float cn = sigm(gs[1])*c_reg + sigm(gs[0])*tanhf(gs[2]);
        c_reg = cn;
        float hn = sigm(gs[3])*tanhf(cn);
        hW[(j>>2)*256 + b*4 + (j&3)] = hn;
      }
    }
    gridbar(cnt, epoch, ++bk, NBLK, true);

    // ============ Phase B: iface GEMM (+ transpose x_{t+1}) ============
    {
      if (bi < 227) {
        const int o0 = bi*2;
        const float4* hp4 = (const float4*)hW;
        const float* w0 = p.Wint + (size_t)o0*HH_ + wv*128;
        const float* w1 = (o0+1 < 453) ? (p.Wint + (size_t)(o0+1)*HH_ + wv*128) : w0;
        float a0 = 0.f, a1 = 0.f;
        #pragma unroll 4
        for (int kk = 0; kk < 32; ++kk) {
          float4 a = hp4[(wv*32 + kk)*64 + b];
          float4 u = *(const float4*)(w0 + kk*4);
          float4 v = *(const float4*)(w1 + kk*4);
          a0 += u.x*a.x + u.y*a.y + u.z*a.z + u.w*a.w;
          a1 += v.x*a.x + v.y*a.y + v.z*a.z + v.w*a.w;
        }
        sm.redB[wv][0][b] = a0;
        sm.redB[wv][1][b] = a1;
      }
      if (bi >= 240 && t+1 < TT_) {
        const int g  = (bi - 240)*NTHR + tid;
        const int bb = g >> 6, kq = g & 63;
        float4 v = *(const float4*)(p.x + (size_t)bb*(TT_*DIN_) + (size_t)(t+1)*DIN_ + 4*kq);
        *(float4*)(p.xbuf + nxt*16384 + kq*256 + bb*4) = v;
      }
      __syncthreads();
      if (bi < 227 && tid < 128) {
        const int jj = tid >> 6;
        const int o  = bi*2 + jj;
        if (o < 453) {
          float s = sm.redB[0][jj][b] + sm.redB[1][jj][b]
                  + sm.redB[2][jj][b] + sm.redB[3][jj][b];
          p.ifc[o*64 + b] = s + p.bint[o];
        }
      }
    }
    gridbar(cnt, epoch, ++bk, 243, (bi < 227) || (bi >= 240));

    // ================= Phase C: content addressing =================
    {
      if (bi < BB_) {
        const int bb   = bi;
        const int lane = b;

        const float wkey = p.ifc[(260+lane)*64 + bb];
        const float er   = sigm(p.ifc[(325+lane)*64 + bb]);
        const float wvec = p.ifc[(389+lane)*64 + bb];
        float rkey[RR_], rstr[RR_], nkr[RR_];
        #pragma unroll
        for (int r = 0; r < RR_; ++r) rkey[r] = p.ifc[(r*64+lane)*64 + bb];
        const float wstr = softp(p.ifc[324*64 + bb]) + 1.f;
        #pragma unroll
        for (int r = 0; r < RR_; ++r) rstr[r] = softp(p.ifc[(256+r)*64 + bb]) + 1.f;

        const float nkw = fmaxf(sqrtf(wredsum(wkey*wkey)), EPSV);
        #pragma unroll
        for (int r = 0; r < RR_; ++r) nkr[r] = fmaxf(sqrtf(wredsum(rkey[r]*rkey[r])), EPSV);
        __syncthreads();

        for (int n = wv; n < NMEM_; n += 4) {
          float m = memS[n][lane];
          float d = wredsum(wkey*m);
          float q = wredsum(m*m);
          if (lane == 0)
            sm.c.aS[n] = wstr * d / (nkw * fmaxf(sqrtf(q), EPSV));
        }
        __syncthreads();

        if (wv == 0) {
          float v0 = sm.c.aS[lane], v1 = sm.c.aS[lane+64];
          float mx = wredmax(fmaxf(v0, v1));
          float e0 = expf(v0-mx), e1 = expf(v1-mx);
          float s  = wredsum(e0+e1);
          sm.c.wwS[lane]    = e0/s;
          sm.c.wwS[lane+64] = e1/s;
        }
        __syncthreads();

        for (int n = wv; n < NMEM_; n += 4) {
          float w  = sm.c.wwS[n];
          float m  = memS[n][lane];
          float mn = m*(1.f - w*er) + w*wvec;
          memS[n][lane] = mn;
          float nm = fmaxf(sqrtf(wredsum(mn*mn)), EPSV);
          #pragma unroll
          for (int r = 0; r < RR_; ++r) {
            float d = wredsum(rkey[r]*mn);
            if (lane == 0) sm.c.rS[r][n] = rstr[r]*d/(nkr[r]*nm);
          }
        }
        __syncthreads();

        {
          float v0 = sm.c.rS[wv][lane], v1 = sm.c.rS[wv][lane+64];
          float mx = wredmax(fmaxf(v0, v1));
          float e0 = expf(v0-mx), e1 = expf(v1-mx);
          float s  = wredsum(e0+e1);
          sm.c.rS[wv][lane]    = e0/s;
          sm.c.rS[wv][lane+64] = e1/s;
        }
        __syncthreads();

        {
          float acc = 0.f;
          for (int n = 0; n < NMEM_; ++n)
            acc += sm.c.rS[wv][n]*memS[n][lane];
          const int k = wv*64 + lane;
          p.rvp[(k>>2)*256 + bb*4 + (k&3)] = acc;
        }
      }
    }
    gridbar(cnt, epoch, ++bk, BB_, bi < BB_);
  }

  // ================= Output projection (last step only) =================
  if (bi < 64) {
    const float4* hp4 = (const float4*)p.hp;      // TT_ even -> final h in hp[0]
    const float4* rp4 = (const float4*)p.rvp;
    const int o0 = bi*4;
    float acc[4] = {0.f, 0.f, 0.f, 0.f};
    #pragma unroll 4
    for (int kk = 0; kk < 48; ++kk) {
      const int k = wv*192 + kk*4;
      float4 a = (k < 512) ? hp4[(k>>2)*64 + b] : rp4[((k-512)>>2)*64 + b];
      #pragma unroll
      for (int r = 0; r < 4; ++r) {
        float4 w = *(const float4*)(p.Wout + (size_t)(o0+r)*(HH_ + RR_*WWID_) + k);
        acc[r] += w.x*a.x + w.y*a.y + w.z*a.z + w.w*a.w;
      }
    }
    #pragma unroll
    for (int r = 0; r < 4; ++r) sm.redO[wv][r][b] = acc[r];
    __syncthreads();
    if (tid < 64) {
      float4 o4;
      float* po = (float*)&o4;
      #pragma unroll
      for (int r = 0; r < 4; ++r)
        po[r] = sm.redO[0][r][b] + sm.redO[1][r][b] + sm.redO[2][r][b]
              + sm.redO[3][r][b] + p.bout[o0+r];
      *(float4*)(p.out + (size_t)b*DOUT_ + o0) = o4;
    }
  }
}

extern "C" void kernel_launch(void* const* d_in, const int* in_sizes, int n_in,
                              void* d_out, int out_size, void* d_ws, size_t ws_size,
                              hipStream_t stream)
{
  Params prm;
  prm.x    = (const float*)d_in[0];
  prm.Wih  = (const float*)d_in[1];
  prm.Whh  = (const float*)d_in[2];
  prm.bih  = (const float*)d_in[3];
  prm.bhh  = (const float*)d_in[4];
  prm.Wint = (const float*)d_in[5];
  prm.bint = (const float*)d_in[6];
  prm.Wout = (const float*)d_in[7];
  prm.bout = (const float*)d_in[8];
  prm.out  = (float*)d_out;

  float* ws = (float*)d_ws;
  size_t off = 0;
  prm.xbuf = ws + off; off += 2*16384;
  prm.hp   = ws + off; off += 2*32768;     // hp, rvp contiguous (zero span)
  prm.rvp  = ws + off; off += 16384;
  prm.ifc  = ws + off; off += 456*64;
  prm.bar  = (unsigned*)(ws + off); off += 64;

  k_initbar<<<1, 64, 0, stream>>>(prm.bar);
  k_persist<<<NBLK, NTHR, 0, stream>>>(prm);
}

// Round 5
// 22504.495 us; speedup vs baseline: 1.9278x; 1.1428x over previous
//
#include <hip/hip_runtime.h>
#include <math.h>

#define BB_   64
#define TT_   256
#define DIN_  256
#define HH_   512
#define NMEM_ 128
#define WWID_ 64
#define RR_   4
#define DOUT_ 256
#define CTRL_ 512
#define EPSV  1e-8f
#define NBLK  256
#define NTHR  256
#define IFLD  456   // ifc row stride (b-major layout)

__device__ __forceinline__ float sigm(float x){ return 1.f/(1.f+expf(-x)); }
__device__ __forceinline__ float softp(float x){ return (x>20.f)? x : log1pf(expf(x)); }
__device__ __forceinline__ float wredsum(float v){
  #pragma unroll
  for (int o=32;o>0;o>>=1) v += __shfl_xor(v,o,64);
  return v;
}
__device__ __forceinline__ float wredmax(float v){
  #pragma unroll
  for (int o=32;o>0;o>>=1) v = fmaxf(v, __shfl_xor(v,o,64));
  return v;
}

// ---- grid barrier: monotonic epoch, relaxed polling, scoped fences ----
__device__ __forceinline__ void gridbar(unsigned* cnt, unsigned* epoch,
                                        unsigned k, unsigned E, bool arrive)
{
  __syncthreads();
  if (threadIdx.x == 0) {
    bool released = false;
    if (arrive) {
      __builtin_amdgcn_fence(__ATOMIC_RELEASE, "agent");
      unsigned a = __hip_atomic_fetch_add(cnt, 1u, __ATOMIC_RELAXED,
                                          __HIP_MEMORY_SCOPE_AGENT);
      if (a == E - 1u) {
        __hip_atomic_store(cnt, 0u, __ATOMIC_RELAXED, __HIP_MEMORY_SCOPE_AGENT);
        __hip_atomic_store(epoch, k, __ATOMIC_RELEASE, __HIP_MEMORY_SCOPE_AGENT);
        released = true;
      }
    }
    if (!released) {
      while (__hip_atomic_load(epoch, __ATOMIC_RELAXED,
                               __HIP_MEMORY_SCOPE_AGENT) < k)
        __builtin_amdgcn_s_sleep(2);
    }
    __builtin_amdgcn_fence(__ATOMIC_ACQUIRE, "agent");
  }
  __syncthreads();
}

__global__ void k_initbar(unsigned* bar){
  if (threadIdx.x == 0) { bar[0] = 0u; bar[32] = 0u; }
}

struct Params {
  const float *x, *Wih, *Whh, *bih, *bhh, *Wint, *bint, *Wout, *bout;
  float *out;
  float *xbuf;   // 2 * 16384  (x_t packed [k/4][b][4])
  float *hp;     // 2 * 32768  (h packed)
  float *rvp;    // 16384      (rv packed)
  float *ifc;    // 64 * IFLD  ([b][o])
  unsigned *bar; // cnt at [0], epoch at [32]
};

union SMu {
  float redA[4][8][64];
  float redB[4][2][64];
  float redO[4][4][64];
  struct {
    float aS[NMEM_];
    float rS[RR_][NMEM_];
    float wwS[NMEM_];
    float ifcS[IFLD];
  } c;
};

__launch_bounds__(NTHR)
__global__ void k_persist(Params p)
{
  __shared__ SMu sm;
  __shared__ float4 wA[4*8*64];          // 32 KB: [wv][r][kk] weight quads
  __shared__ float4 wB[2*128];           // 4 KB:  [jj][kk] W_int rows
  __shared__ float  memS[NMEM_][WWID_];  // 32 KB: persistent DNC memory

  const int bi  = blockIdx.x;
  const int tid = threadIdx.x;
  const int b   = tid & 63;
  const int wv  = tid >> 6;
  const int j0  = bi*2;

  unsigned* cnt   = p.bar;
  unsigned* epoch = p.bar + 32;

  float c_reg = 0.f;                     // LSTM cell state (tid<128)

  // ---- one-time: stage weights to LDS, biases to regs, zero state ----
  for (int i = tid; i < 2048; i += NTHR) {
    const int w_ = i >> 9;               // 0..3 (wave slot)
    const int r  = (i >> 6) & 7;         // row: g*2+jj
    const int kk = i & 63;
    const int g = r >> 1, jj = r & 1;
    const float* base = (w_ < 2) ? p.Wih : p.Whh;   // CTRL_==HH_==512 stride
    wA[i] = *(const float4*)(base + (size_t)(g*HH_ + j0 + jj)*CTRL_
                              + (w_ & 1)*256 + kk*4);
  }
  if (bi < 227) {
    const int jj = tid >> 7, kk = tid & 127;        // one float4 per thread
    const int o = (j0 + jj < 453) ? (j0 + jj) : 452;
    wB[tid] = *(const float4*)(p.Wint + (size_t)o*HH_ + kk*4);
  }
  float bsum[4];                         // gate biases (tid<128)
  if (tid < 128) {
    const int j = j0 + (tid >> 6);
    #pragma unroll
    for (int g = 0; g < 4; ++g)
      bsum[g] = p.bih[g*HH_ + j] + p.bhh[g*HH_ + j];
  }
  float bint_r = 0.f;                    // iface bias (tid<128, bi<227)
  if (bi < 227 && tid < 128) {
    const int o = j0 + (tid >> 6);
    if (o < 453) bint_r = p.bint[o];
  }
  {
    float4* z = (float4*)p.hp;           // hp, rvp contiguous in ws
    const int nz4 = (2*HH_*64 + RR_*WWID_*64) >> 2;
    for (int i = bi*NTHR + tid; i < nz4; i += NBLK*NTHR)
      z[i] = make_float4(0.f, 0.f, 0.f, 0.f);
    for (int i = tid; i < NMEM_*WWID_; i += NTHR)
      ((float*)memS)[i] = 0.f;
    if (bi >= 240) {
      const int g  = (bi - 240)*NTHR + tid;
      const int bb = g >> 6, kq = g & 63;
      float4 v = *(const float4*)(p.x + (size_t)bb*(TT_*DIN_) + 4*kq);
      *(float4*)(p.xbuf + kq*256 + bb*4) = v;
    }
  }
  unsigned bk = 1;
  gridbar(cnt, epoch, bk, NBLK, true);

  for (int t = 0; t < TT_; ++t) {
    const int cur = t & 1, nxt = cur ^ 1;
    const float* hR = p.hp + cur*32768;
    float*       hW = p.hp + nxt*32768;

    // ================= Phase A: gates GEMM + LSTM =================
    {
      const float4* ap;
      if      (wv == 0) ap = (const float4*)(p.xbuf + cur*16384);
      else if (wv == 1) ap = (const float4*)p.rvp;
      else if (wv == 2) ap = (const float4*)hR;
      else              ap = (const float4*)(hR + 16384);
      const float4* wvw = wA + (wv << 9);   // 512 quads: [r][kk]

      float acc[8];
      #pragma unroll
      for (int r = 0; r < 8; ++r) acc[r] = 0.f;

      #pragma unroll 4
      for (int kk = 0; kk < 64; ++kk) {
        float4 a = ap[kk*64 + b];
        #pragma unroll
        for (int r = 0; r < 8; ++r) {
          float4 w = wvw[(r << 6) + kk];    // ds_read_b128, lane-broadcast
          acc[r] += w.x*a.x + w.y*a.y + w.z*a.z + w.w*a.w;
        }
      }
      #pragma unroll
      for (int r = 0; r < 8; ++r) sm.redA[wv][r][b] = acc[r];
      __syncthreads();

      if (tid < 128) {
        const int jj = tid >> 6;
        const int j  = j0 + jj;
        float gs[4];
        #pragma unroll
        for (int g = 0; g < 4; ++g)
          gs[g] = sm.redA[0][g*2+jj][b] + sm.redA[1][g*2+jj][b]
                + sm.redA[2][g*2+jj][b] + sm.redA[3][g*2+jj][b] + bsum[g];
        float cn = sigm(gs[1])*c_reg + sigm(gs[0])*tanhf(gs[2]);
        c_reg = cn;
        float hn = sigm(gs[3])*tanhf(cn);
        hW[(j>>2)*256 + b*4 + (j&3)] = hn;
      }
    }
    gridbar(cnt, epoch, ++bk, NBLK, true);

    // ============ Phase B: iface GEMM (+ transpose x_{t+1}) ============
    {
      if (bi < 227) {
        const float4* hp4 = (const float4*)hW;
        const float4* w0 = wB + wv*32;
        const float4* w1 = wB + 128 + wv*32;
        float a0 = 0.f, a1 = 0.f;
        #pragma unroll 4
        for (int kk = 0; kk < 32; ++kk) {
          float4 a = hp4[(wv*32 + kk)*64 + b];
          float4 u = w0[kk];
          float4 v = w1[kk];
          a0 += u.x*a.x + u.y*a.y + u.z*a.z + u.w*a.w;
          a1 += v.x*a.x + v.y*a.y + v.z*a.z + v.w*a.w;
        }
        sm.redB[wv][0][b] = a0;
        sm.redB[wv][1][b] = a1;
      }
      if (bi >= 240 && t+1 < TT_) {
        const int g  = (bi - 240)*NTHR + tid;
        const int bb = g >> 6, kq = g & 63;
        float4 v = *(const float4*)(p.x + (size_t)bb*(TT_*DIN_) + (size_t)(t+1)*DIN_ + 4*kq);
        *(float4*)(p.xbuf + nxt*16384 + kq*256 + bb*4) = v;
      }
      __syncthreads();
      if (bi < 227 && tid < 128) {
        const int jj = tid >> 6;
        const int o  = j0 + jj;
        if (o < 453) {
          float s = sm.redB[0][jj][b] + sm.redB[1][jj][b]
                  + sm.redB[2][jj][b] + sm.redB[3][jj][b];
          p.ifc[(size_t)b*IFLD + o] = s + bint_r;   // b-major
        }
      }
    }
    gridbar(cnt, epoch, ++bk, 243, (bi < 227) || (bi >= 240));

    // ================= Phase C: content addressing =================
    {
      if (bi < BB_) {
        const int bb   = bi;
        const int lane = b;

        for (int i = tid; i < IFLD; i += NTHR)      // coalesced row load
          sm.c.ifcS[i] = p.ifc[(size_t)bb*IFLD + i];
        __syncthreads();

        const float wkey = sm.c.ifcS[260+lane];
        const float er   = sigm(sm.c.ifcS[325+lane]);
        const float wvec = sm.c.ifcS[389+lane];
        float rkey[RR_], rstr[RR_], nkr[RR_];
        #pragma unroll
        for (int r = 0; r < RR_; ++r) rkey[r] = sm.c.ifcS[r*64+lane];
        const float wstr = softp(sm.c.ifcS[324]) + 1.f;
        #pragma unroll
        for (int r = 0; r < RR_; ++r) rstr[r] = softp(sm.c.ifcS[256+r]) + 1.f;

        const float nkw = fmaxf(sqrtf(wredsum(wkey*wkey)), EPSV);
        #pragma unroll
        for (int r = 0; r < RR_; ++r) nkr[r] = fmaxf(sqrtf(wredsum(rkey[r]*rkey[r])), EPSV);
        __syncthreads();

        for (int n = wv; n < NMEM_; n += 4) {
          float m = memS[n][lane];
          float d = wredsum(wkey*m);
          float q = wredsum(m*m);
          if (lane == 0)
            sm.c.aS[n] = wstr * d / (nkw * fmaxf(sqrtf(q), EPSV));
        }
        __syncthreads();

        if (wv == 0) {
          float v0 = sm.c.aS[lane], v1 = sm.c.aS[lane+64];
          float mx = wredmax(fmaxf(v0, v1));
          float e0 = expf(v0-mx), e1 = expf(v1-mx);
          float s  = wredsum(e0+e1);
          sm.c.wwS[lane]    = e0/s;
          sm.c.wwS[lane+64] = e1/s;
        }
        __syncthreads();

        for (int n = wv; n < NMEM_; n += 4) {
          float w  = sm.c.wwS[n];
          float m  = memS[n][lane];
          float mn = m*(1.f - w*er) + w*wvec;
          memS[n][lane] = mn;
          float nm = fmaxf(sqrtf(wredsum(mn*mn)), EPSV);
          #pragma unroll
          for (int r = 0; r < RR_; ++r) {
            float d = wredsum(rkey[r]*mn);
            if (lane == 0) sm.c.rS[r][n] = rstr[r]*d/(nkr[r]*nm);
          }
        }
        __syncthreads();

        {
          float v0 = sm.c.rS[wv][lane], v1 = sm.c.rS[wv][lane+64];
          float mx = wredmax(fmaxf(v0, v1));
          float e0 = expf(v0-mx), e1 = expf(v1-mx);
          float s  = wredsum(e0+e1);
          sm.c.rS[wv][lane]    = e0/s;
          sm.c.rS[wv][lane+64] = e1/s;
        }
        __syncthreads();

        {
          float acc = 0.f;
          for (int n = 0; n < NMEM_; ++n)
            acc += sm.c.rS[wv][n]*memS[n][lane];
          const int k = wv*64 + lane;
          p.rvp[(k>>2)*256 + bb*4 + (k&3)] = acc;
        }
      }
    }
    gridbar(cnt, epoch, ++bk, BB_, bi < BB_);
  }

  // ================= Output projection (last step only) =================
  if (bi < 64) {
    const float4* hp4 = (const float4*)p.hp;      // TT_ even -> final h in hp[0]
    const float4* rp4 = (const float4*)p.rvp;
    const int o0 = bi*4;
    float acc[4] = {0.f, 0.f, 0.f, 0.f};
    #pragma unroll 4
    for (int kk = 0; kk < 48; ++kk) {
      const int k = wv*192 + kk*4;
      float4 a = (k < 512) ? hp4[(k>>2)*64 + b] : rp4[((k-512)>>2)*64 + b];
      #pragma unroll
      for (int r = 0; r < 4; ++r) {
        float4 w = *(const float4*)(p.Wout + (size_t)(o0+r)*(HH_ + RR_*WWID_) + k);
        acc[r] += w.x*a.x + w.y*a.y + w.z*a.z + w.w*a.w;
      }
    }
    #pragma unroll
    for (int r = 0; r < 4; ++r) sm.redO[wv][r][b] = acc[r];
    __syncthreads();
    if (tid < 64) {
      float4 o4;
      float* po = (float*)&o4;
      #pragma unroll
      for (int r = 0; r < 4; ++r)
        po[r] = sm.redO[0][r][b] + sm.redO[1][r][b] + sm.redO[2][r][b]
              + sm.redO[3][r][b] + p.bout[o0+r];
      *(float4*)(p.out + (size_t)b*DOUT_ + o0) = o4;
    }
  }
}

extern "C" void kernel_launch(void* const* d_in, const int* in_sizes, int n_in,
                              void* d_out, int out_size, void* d_ws, size_t ws_size,
                              hipStream_t stream)
{
  Params prm;
  prm.x    = (const float*)d_in[0];
  prm.Wih  = (const float*)d_in[1];
  prm.Whh  = (const float*)d_in[2];
  prm.bih  = (const float*)d_in[3];
  prm.bhh  = (const float*)d_in[4];
  prm.Wint = (const float*)d_in[5];
  prm.bint = (const float*)d_in[6];
  prm.Wout = (const float*)d_in[7];
  prm.bout = (const float*)d_in[8];
  prm.out  = (float*)d_out;

  float* ws = (float*)d_ws;
  size_t off = 0;
  prm.xbuf = ws + off; off += 2*16384;
  prm.hp   = ws + off; off += 2*32768;     // hp, rvp contiguous (zero span)
  prm.rvp  = ws + off; off += 16384;
  prm.ifc  = ws + off; off += 64*IFLD;
  prm.bar  = (unsigned*)(ws + off); off += 64;

  k_initbar<<<1, 64, 0, stream>>>(prm.bar);
  k_persist<<<NBLK, NTHR, 0, stream>>>(prm);
}

// Round 6
// 18747.163 us; speedup vs baseline: 2.3141x; 1.2004x over previous
//
#include <hip/hip_runtime.h>
#include <math.h>

#define BB_   64
#define TT_   256
#define DIN_  256
#define HH_   512
#define NMEM_ 128
#define WWID_ 64
#define RR_   4
#define DOUT_ 256
#define CTRL_ 512
#define EPSV  1e-8f
#define NBLK  256
#define NTHR  256
#define IFLD  456   // ifc row stride (b-major layout)

__device__ __forceinline__ float sigm(float x){ return 1.f/(1.f+expf(-x)); }
__device__ __forceinline__ float softp(float x){ return (x>20.f)? x : log1pf(expf(x)); }
__device__ __forceinline__ float wredsum(float v){
  #pragma unroll
  for (int o=32;o>0;o>>=1) v += __shfl_xor(v,o,64);
  return v;
}
__device__ __forceinline__ float wredmax(float v){
  #pragma unroll
  for (int o=32;o>0;o>>=1) v = fmaxf(v, __shfl_xor(v,o,64));
  return v;
}

// ---- LLC-coherent accessors: relaxed agent-scope atomics -> sc0/sc1 ops that
// bypass the non-coherent per-XCD L2s. No fences -> no buffer_wbl2/inv ever. ----
__device__ __forceinline__ float2 cload2(const float* p){
  unsigned long long u = __hip_atomic_load((const unsigned long long*)p,
                          __ATOMIC_RELAXED, __HIP_MEMORY_SCOPE_AGENT);
  float2 r; __builtin_memcpy(&r, &u, 8); return r;
}
__device__ __forceinline__ void cstore2(float* p, float2 v){
  unsigned long long u; __builtin_memcpy(&u, &v, 8);
  __hip_atomic_store((unsigned long long*)p, u, __ATOMIC_RELAXED,
                     __HIP_MEMORY_SCOPE_AGENT);
}
__device__ __forceinline__ void cstore1(float* p, float v){
  unsigned u; __builtin_memcpy(&u, &v, 4);
  __hip_atomic_store((unsigned*)p, u, __ATOMIC_RELAXED, __HIP_MEMORY_SCOPE_AGENT);
}

// ---- fence-free grid barrier: monotonic counters, 2-level tree ----
// layout in bar[]: grp g at [g*32] (g=0..7), root at [256], epoch at [288]
__device__ __forceinline__ void gridbar(unsigned* bar, unsigned k)
{
  __syncthreads();                       // drains vmcnt -> payload at LLC
  if (threadIdx.x == 0) {
    const int g = blockIdx.x >> 5;
    unsigned a = __hip_atomic_fetch_add(bar + g*32, 1u, __ATOMIC_RELAXED,
                                        __HIP_MEMORY_SCOPE_AGENT);
    bool released = false;
    if (a == 32u*k - 1u) {               // last arrival of this group
      unsigned r = __hip_atomic_fetch_add(bar + 256, 1u, __ATOMIC_RELAXED,
                                          __HIP_MEMORY_SCOPE_AGENT);
      if (r == 8u*k - 1u) {              // last group -> publish epoch
        __hip_atomic_store(bar + 288, k, __ATOMIC_RELAXED,
                           __HIP_MEMORY_SCOPE_AGENT);
        released = true;
      }
    }
    if (!released) {
      while (__hip_atomic_load(bar + 288, __ATOMIC_RELAXED,
                               __HIP_MEMORY_SCOPE_AGENT) < k)
        __builtin_amdgcn_s_sleep(1);
    }
  }
  __syncthreads();
}

__global__ void k_initbar(unsigned* bar){
  int i = threadIdx.x;
  if (i < 320)
    __hip_atomic_store(bar + i, 0u, __ATOMIC_RELAXED, __HIP_MEMORY_SCOPE_AGENT);
}

struct Params {
  const float *x, *Wih, *Whh, *bih, *bhh, *Wint, *bint, *Wout, *bout;
  float *out;
  float *xbuf;   // 2 * 16384  (x_t packed [k/4][b][4])
  float *hp;     // 2 * 32768  (h packed)
  float *rvp;    // 16384      (rv packed)
  float *ifc;    // 64 * IFLD  ([b][o])
  unsigned *bar;
};

union SMu {
  float redA[4][8][64];
  float redO[4][4][64];
  struct {
    float aS[NMEM_];
    float rS[RR_][NMEM_];
    float wwS[NMEM_];
    float ifcS[IFLD];
  } c;
};

__launch_bounds__(NTHR)
__global__ void k_persist(Params p)
{
  __shared__ SMu sm;
  __shared__ float4 wA[4*8*64];          // 32 KB gates-weight slice
  __shared__ float4 wB[8*128];           // 16 KB W_int slice (8 rows)
  __shared__ float  memS[NMEM_][WWID_];  // 32 KB persistent DNC memory

  const int bi  = blockIdx.x;
  const int tid = threadIdx.x;
  const int b   = tid & 63;
  const int wv  = tid >> 6;
  const int j0  = bi*2;

  float c_reg = 0.f;                     // LSTM cell state (tid<128)

  // ---- one-time staging: weights -> LDS, biases -> regs, zero state ----
  for (int i = tid; i < 2048; i += NTHR) {
    const int w_ = i >> 9;
    const int r  = (i >> 6) & 7;
    const int kk = i & 63;
    const int g = r >> 1, jj = r & 1;
    const float* base = (w_ < 2) ? p.Wih : p.Whh;
    wA[i] = *(const float4*)(base + (size_t)(g*HH_ + j0 + jj)*CTRL_
                              + (w_ & 1)*256 + kk*4);
  }
  if (bi < 57) {
    for (int i = tid; i < 1024; i += NTHR) {
      const int r = i >> 7, kk = i & 127;
      int o = bi*8 + r; if (o > 452) o = 452;
      wB[i] = *(const float4*)(p.Wint + (size_t)o*HH_ + kk*4);
    }
  }
  float bsum[4];
  if (tid < 128) {
    const int j = j0 + (tid >> 6);
    #pragma unroll
    for (int g = 0; g < 4; ++g)
      bsum[g] = p.bih[g*HH_ + j] + p.bhh[g*HH_ + j];
  }
  float bintB[2] = {0.f, 0.f};
  if (bi < 57) {
    const int r0 = tid >> 6;
    if (bi*8 + r0     < 453) bintB[0] = p.bint[bi*8 + r0];
    if (bi*8 + r0 + 4 < 453) bintB[1] = p.bint[bi*8 + r0 + 4];
  }
  {
    const float2 zz = make_float2(0.f, 0.f);
    const int gt = bi*NTHR + tid;
    if      (gt < 16384) cstore2(p.hp  + 2*gt,          zz);   // h0
    else if (gt < 24576) cstore2(p.rvp + 2*(gt-16384),  zz);   // rv
    for (int i = tid; i < NMEM_*WWID_; i += NTHR)
      ((float*)memS)[i] = 0.f;
    if (bi >= 240) {
      const int g  = (bi - 240)*NTHR + tid;
      const int bb = g >> 6, kq = g & 63;
      float4 v = *(const float4*)(p.x + (size_t)bb*(TT_*DIN_) + 4*kq);
      float* d = p.xbuf + kq*256 + bb*4;
      cstore2(d,   make_float2(v.x, v.y));
      cstore2(d+2, make_float2(v.z, v.w));
    }
  }
  unsigned bk = 1;
  gridbar(p.bar, bk);

  for (int t = 0; t < TT_; ++t) {
    const int cur = t & 1, nxt = cur ^ 1;
    const float* hR = p.hp + cur*32768;
    float*       hW = p.hp + nxt*32768;

    // ================= Phase A: gates GEMM + LSTM =================
    {
      const float* ap;
      if      (wv == 0) ap = p.xbuf + cur*16384;
      else if (wv == 1) ap = p.rvp;
      else if (wv == 2) ap = hR;
      else              ap = hR + 16384;
      const float4* wvw = wA + (wv << 9);

      float acc[8];
      #pragma unroll
      for (int r = 0; r < 8; ++r) acc[r] = 0.f;

      #pragma unroll 4
      for (int kk = 0; kk < 64; ++kk) {
        const float* a8 = ap + (((kk << 6) + b) << 2);
        float2 alo = cload2(a8);
        float2 ahi = cload2(a8 + 2);
        #pragma unroll
        for (int r = 0; r < 8; ++r) {
          float4 w = wvw[(r << 6) + kk];
          acc[r] += w.x*alo.x + w.y*alo.y + w.z*ahi.x + w.w*ahi.y;
        }
      }
      #pragma unroll
      for (int r = 0; r < 8; ++r) sm.redA[wv][r][b] = acc[r];
      __syncthreads();

      if (tid < 128) {
        const int jj = tid >> 6;
        const int j  = j0 + jj;
        float gs[4];
        #pragma unroll
        for (int g = 0; g < 4; ++g)
          gs[g] = sm.redA[0][g*2+jj][b] + sm.redA[1][g*2+jj][b]
                + sm.redA[2][g*2+jj][b] + sm.redA[3][g*2+jj][b] + bsum[g];
        float cn = sigm(gs[1])*c_reg + sigm(gs[0])*tanhf(gs[2]);
        c_reg = cn;
        float hn = sigm(gs[3])*tanhf(cn);
        cstore1(hW + (j>>2)*256 + b*4 + (j&3), hn);
      }
    }
    gridbar(p.bar, ++bk);

    // ============ Phase B: iface GEMM (+ transpose x_{t+1}) ============
    {
      if (bi < 57) {
        float accB[8];
        #pragma unroll
        for (int r = 0; r < 8; ++r) accB[r] = 0.f;
        #pragma unroll 4
        for (int kk = 0; kk < 32; ++kk) {
          const float* h8 = hW + (((((wv<<5)+kk) << 6) + b) << 2);
          float2 alo = cload2(h8);
          float2 ahi = cload2(h8 + 2);
          #pragma unroll
          for (int r = 0; r < 8; ++r) {
            float4 w = wB[(r << 7) + (wv << 5) + kk];
            accB[r] += w.x*alo.x + w.y*alo.y + w.z*ahi.x + w.w*ahi.y;
          }
        }
        #pragma unroll
        for (int r = 0; r < 8; ++r) sm.redA[wv][r][b] = accB[r];
        __syncthreads();
        {
          const int r0 = tid >> 6;
          #pragma unroll
          for (int half = 0; half < 2; ++half) {
            const int r = r0 + half*4;
            const int o = bi*8 + r;
            if (o < 453) {
              float s = sm.redA[0][r][b] + sm.redA[1][r][b]
                      + sm.redA[2][r][b] + sm.redA[3][r][b] + bintB[half];
              cstore1(p.ifc + (size_t)b*IFLD + o, s);
            }
          }
        }
      }
      if (bi >= 240 && t+1 < TT_) {
        const int g  = (bi - 240)*NTHR + tid;
        const int bb = g >> 6, kq = g & 63;
        float4 v = *(const float4*)(p.x + (size_t)bb*(TT_*DIN_)
                                    + (size_t)(t+1)*DIN_ + 4*kq);
        float* d = p.xbuf + nxt*16384 + kq*256 + bb*4;
        cstore2(d,   make_float2(v.x, v.y));
        cstore2(d+2, make_float2(v.z, v.w));
      }
    }
    gridbar(p.bar, ++bk);

    // ================= Phase C: content addressing =================
    {
      if (bi < BB_) {
        const int bb   = bi;
        const int lane = b;

        for (int i = tid; i < 228; i += NTHR) {
          float2 v = cload2(p.ifc + (size_t)bb*IFLD + 2*i);
          sm.c.ifcS[2*i]   = v.x;
          sm.c.ifcS[2*i+1] = v.y;
        }
        __syncthreads();

        const float wkey = sm.c.ifcS[260+lane];
        const float er   = sigm(sm.c.ifcS[325+lane]);
        const float wvec = sm.c.ifcS[389+lane];
        float rkey[RR_], rstr[RR_], nkr[RR_];
        #pragma unroll
        for (int r = 0; r < RR_; ++r) rkey[r] = sm.c.ifcS[r*64+lane];
        const float wstr = softp(sm.c.ifcS[324]) + 1.f;
        #pragma unroll
        for (int r = 0; r < RR_; ++r) rstr[r] = softp(sm.c.ifcS[256+r]) + 1.f;

        const float nkw = fmaxf(sqrtf(wredsum(wkey*wkey)), EPSV);
        #pragma unroll
        for (int r = 0; r < RR_; ++r) nkr[r] = fmaxf(sqrtf(wredsum(rkey[r]*rkey[r])), EPSV);
        __syncthreads();

        for (int n = wv; n < NMEM_; n += 4) {
          float m = memS[n][lane];
          float d = wredsum(wkey*m);
          float q = wredsum(m*m);
          if (lane == 0)
            sm.c.aS[n] = wstr * d / (nkw * fmaxf(sqrtf(q), EPSV));
        }
        __syncthreads();

        if (wv == 0) {
          float v0 = sm.c.aS[lane], v1 = sm.c.aS[lane+64];
          float mx = wredmax(fmaxf(v0, v1));
          float e0 = expf(v0-mx), e1 = expf(v1-mx);
          float s  = wredsum(e0+e1);
          sm.c.wwS[lane]    = e0/s;
          sm.c.wwS[lane+64] = e1/s;
        }
        __syncthreads();

        for (int n = wv; n < NMEM_; n += 4) {
          float w  = sm.c.wwS[n];
          float m  = memS[n][lane];
          float mn = m*(1.f - w*er) + w*wvec;
          memS[n][lane] = mn;
          float nm = fmaxf(sqrtf(wredsum(mn*mn)), EPSV);
          #pragma unroll
          for (int r = 0; r < RR_; ++r) {
            float d = wredsum(rkey[r]*mn);
            if (lane == 0) sm.c.rS[r][n] = rstr[r]*d/(nkr[r]*nm);
          }
        }
        __syncthreads();

        {
          float v0 = sm.c.rS[wv][lane], v1 = sm.c.rS[wv][lane+64];
          float mx = wredmax(fmaxf(v0, v1));
          float e0 = expf(v0-mx), e1 = expf(v1-mx);
          float s  = wredsum(e0+e1);
          sm.c.rS[wv][lane]    = e0/s;
          sm.c.rS[wv][lane+64] = e1/s;
        }
        __syncthreads();

        {
          float acc = 0.f;
          for (int n = 0; n < NMEM_; ++n)
            acc += sm.c.rS[wv][n]*memS[n][lane];
          const int k = wv*64 + lane;
          cstore1(p.rvp + (k>>2)*256 + bb*4 + (k&3), acc);
        }
      }
    }
    gridbar(p.bar, ++bk);
  }

  // ================= Output projection (last step only) =================
  if (bi < 64) {
    const int o0 = bi*4;
    float acc[4] = {0.f, 0.f, 0.f, 0.f};
    #pragma unroll 4
    for (int kk = 0; kk < 48; ++kk) {
      const int k = wv*192 + kk*4;
      const float* a8 = (k < 512)
        ? (p.hp  + ((((k    )>>2) << 6) + b)*4)     // final h lives in hp[0]
        : (p.rvp + ((((k-512)>>2) << 6) + b)*4);
      float2 alo = cload2(a8);
      float2 ahi = cload2(a8 + 2);
      #pragma unroll
      for (int r = 0; r < 4; ++r) {
        float4 w = *(const float4*)(p.Wout + (size_t)(o0+r)*(HH_ + RR_*WWID_) + k);
        acc[r] += w.x*alo.x + w.y*alo.y + w.z*ahi.x + w.w*ahi.y;
      }
    }
    #pragma unroll
    for (int r = 0; r < 4; ++r) sm.redO[wv][r][b] = acc[r];
    __syncthreads();
    if (tid < 64) {
      float4 o4;
      float* po = (float*)&o4;
      #pragma unroll
      for (int r = 0; r < 4; ++r)
        po[r] = sm.redO[0][r][b] + sm.redO[1][r][b] + sm.redO[2][r][b]
              + sm.redO[3][r][b] + p.bout[o0+r];
      *(float4*)(p.out + (size_t)b*DOUT_ + o0) = o4;
    }
  }
}

extern "C" void kernel_launch(void* const* d_in, const int* in_sizes, int n_in,
                              void* d_out, int out_size, void* d_ws, size_t ws_size,
                              hipStream_t stream)
{
  Params prm;
  prm.x    = (const float*)d_in[0];
  prm.Wih  = (const float*)d_in[1];
  prm.Whh  = (const float*)d_in[2];
  prm.bih  = (const float*)d_in[3];
  prm.bhh  = (const float*)d_in[4];
  prm.Wint = (const float*)d_in[5];
  prm.bint = (const float*)d_in[6];
  prm.Wout = (const float*)d_in[7];
  prm.bout = (const float*)d_in[8];
  prm.out  = (float*)d_out;

  float* ws = (float*)d_ws;
  size_t off = 0;
  prm.xbuf = ws + off; off += 2*16384;
  prm.hp   = ws + off; off += 2*32768;
  prm.rvp  = ws + off; off += 16384;
  prm.ifc  = ws + off; off += 64*IFLD;
  prm.bar  = (unsigned*)(ws + off); off += 512;

  k_initbar<<<1, 512, 0, stream>>>(prm.bar);
  k_persist<<<NBLK, NTHR, 0, stream>>>(prm);
}

// Round 7
// 11547.849 us; speedup vs baseline: 3.7568x; 1.6234x over previous
//
#include <hip/hip_runtime.h>
#include <math.h>

#define BB_   64
#define TT_   256
#define DIN_  256
#define HH_   512
#define NMEM_ 128
#define WWID_ 64
#define RR_   4
#define DOUT_ 256
#define CTRL_ 512
#define EPSV  1e-8f
#define NBLK  256
#define NTHR  256
#define IFLD  456   // ifc row stride (b-major layout)
#define MPAD  65    // padded mem stride: bank = (n+w)%32

__device__ __forceinline__ float sigm(float x){ return 1.f/(1.f+expf(-x)); }
__device__ __forceinline__ float softp(float x){ return (x>20.f)? x : log1pf(expf(x)); }
__device__ __forceinline__ float wredsum(float v){
  #pragma unroll
  for (int o=32;o>0;o>>=1) v += __shfl_xor(v,o,64);
  return v;
}
__device__ __forceinline__ float wredmax(float v){
  #pragma unroll
  for (int o=32;o>0;o>>=1) v = fmaxf(v, __shfl_xor(v,o,64));
  return v;
}

// ---- LLC-coherent accessors: relaxed agent-scope atomics (bypass per-XCD L2) ----
__device__ __forceinline__ float2 cload2(const float* p){
  unsigned long long u = __hip_atomic_load((const unsigned long long*)p,
                          __ATOMIC_RELAXED, __HIP_MEMORY_SCOPE_AGENT);
  float2 r; __builtin_memcpy(&r, &u, 8); return r;
}
__device__ __forceinline__ void cstore2(float* p, float2 v){
  unsigned long long u; __builtin_memcpy(&u, &v, 8);
  __hip_atomic_store((unsigned long long*)p, u, __ATOMIC_RELAXED,
                     __HIP_MEMORY_SCOPE_AGENT);
}
__device__ __forceinline__ void cstore1(float* p, float v){
  unsigned u; __builtin_memcpy(&u, &v, 4);
  __hip_atomic_store((unsigned*)p, u, __ATOMIC_RELAXED, __HIP_MEMORY_SCOPE_AGENT);
}

// ---- fence-free grid barrier: monotonic counters, 2-level tree ----
__device__ __forceinline__ void gridbar(unsigned* bar, unsigned k)
{
  __syncthreads();
  if (threadIdx.x == 0) {
    const int g = blockIdx.x >> 5;
    unsigned a = __hip_atomic_fetch_add(bar + g*32, 1u, __ATOMIC_RELAXED,
                                        __HIP_MEMORY_SCOPE_AGENT);
    bool released = false;
    if (a == 32u*k - 1u) {
      unsigned r = __hip_atomic_fetch_add(bar + 256, 1u, __ATOMIC_RELAXED,
                                          __HIP_MEMORY_SCOPE_AGENT);
      if (r == 8u*k - 1u) {
        __hip_atomic_store(bar + 288, k, __ATOMIC_RELAXED,
                           __HIP_MEMORY_SCOPE_AGENT);
        released = true;
      }
    }
    if (!released) {
      while (__hip_atomic_load(bar + 288, __ATOMIC_RELAXED,
                               __HIP_MEMORY_SCOPE_AGENT) < k)
        __builtin_amdgcn_s_sleep(1);
    }
  }
  __syncthreads();
}

__global__ void k_initbar(unsigned* bar){
  int i = threadIdx.x;
  if (i < 320)
    __hip_atomic_store(bar + i, 0u, __ATOMIC_RELAXED, __HIP_MEMORY_SCOPE_AGENT);
}

struct Params {
  const float *x, *Wih, *Whh, *bih, *bhh, *Wint, *bint, *Wout, *bout;
  float *out;
  float *xbuf;   // 2 * 16384  (x_t packed [k/4][b][4])
  float *hp;     // 2 * 32768  (h packed)
  float *rvp;    // 16384      (rv packed)
  float *ifc;    // 64 * IFLD  ([b][o])
  unsigned *bar;
};

union SMu {
  float redA[4][8][64];
  float redO[4][4][64];
  struct {
    float ifcS[IFLD];
    float kpk[WWID_][8];     // [w]: wkey, rk0..3, er, wvec, pad
    float dH[2][NMEM_];
    float qH[2][NMEM_];
    float nH[2][NMEM_];
    float drH[2][RR_][NMEM_];
    float wwS[NMEM_];
    float rwS[RR_][NMEM_];
    float scal[8];           // nkw, nkr0..3
    float red2[8];
  } c;
};

__launch_bounds__(NTHR)
__global__ void k_persist(Params p)
{
  __shared__ SMu sm;
  __shared__ float memS[NMEM_][MPAD];   // persistent DNC memory, padded

  const int bi  = blockIdx.x;
  const int tid = threadIdx.x;
  const int b   = tid & 63;
  const int wv  = tid >> 6;
  const int j0  = bi*2;

  float c_reg = 0.f;                    // LSTM cell state (tid<128)

  // gate-weight row pointers (L2-cached plain loads; never invalidated)
  const float* wb[8];
  {
    const float* Wsrc = (wv < 2) ? p.Wih : p.Whh;
    const int koff = (wv & 1) * 256;
    #pragma unroll
    for (int g = 0; g < 4; ++g)
      #pragma unroll
      for (int jj = 0; jj < 2; ++jj)
        wb[g*2+jj] = Wsrc + (size_t)(g*HH_ + j0 + jj)*CTRL_ + koff;
  }
  const float* wbB[8];
  if (bi < 57) {
    #pragma unroll
    for (int r = 0; r < 8; ++r) {
      int o = bi*8 + r; if (o > 452) o = 452;
      wbB[r] = p.Wint + (size_t)o*HH_ + wv*128;
    }
  }
  float bsum[4];
  if (tid < 128) {
    const int j = j0 + (tid >> 6);
    #pragma unroll
    for (int g = 0; g < 4; ++g)
      bsum[g] = p.bih[g*HH_ + j] + p.bhh[g*HH_ + j];
  }
  float bintB[2] = {0.f, 0.f};
  if (bi < 57) {
    const int r0 = tid >> 6;
    if (bi*8 + r0     < 453) bintB[0] = p.bint[bi*8 + r0];
    if (bi*8 + r0 + 4 < 453) bintB[1] = p.bint[bi*8 + r0 + 4];
  }
  // ---- init: zero state, transpose x_0 ----
  {
    const float2 zz = make_float2(0.f, 0.f);
    const int gt = bi*NTHR + tid;
    if      (gt < 16384) cstore2(p.hp  + 2*gt,          zz);   // h0
    else if (gt < 24576) cstore2(p.rvp + 2*(gt-16384),  zz);   // rv
    for (int i = tid; i < NMEM_*MPAD; i += NTHR)
      ((float*)memS)[i] = 0.f;
    if (bi >= 240) {
      const int g  = (bi - 240)*NTHR + tid;
      const int bb = g >> 6, kq = g & 63;
      float4 v = *(const float4*)(p.x + (size_t)bb*(TT_*DIN_) + 4*kq);
      float* d = p.xbuf + kq*256 + bb*4;
      cstore2(d,   make_float2(v.x, v.y));
      cstore2(d+2, make_float2(v.z, v.w));
    }
  }
  unsigned bk = 1;
  gridbar(p.bar, bk);

  for (int t = 0; t < TT_; ++t) {
    const int cur = t & 1, nxt = cur ^ 1;
    const float* hR = p.hp + cur*32768;
    float*       hW = p.hp + nxt*32768;

    // ================= Phase A: gates GEMM + LSTM =================
    {
      const float* ap;
      if      (wv == 0) ap = p.xbuf + cur*16384;
      else if (wv == 1) ap = p.rvp;
      else if (wv == 2) ap = hR;
      else              ap = hR + 16384;

      float acc[8];
      #pragma unroll
      for (int r = 0; r < 8; ++r) acc[r] = 0.f;

      #pragma unroll 4
      for (int kk = 0; kk < 64; ++kk) {
        const float* a8 = ap + (((kk << 6) + b) << 2);
        float2 alo = cload2(a8);
        float2 ahi = cload2(a8 + 2);
        #pragma unroll
        for (int r = 0; r < 8; ++r) {
          float4 w = *(const float4*)(wb[r] + kk*4);   // L2-warm broadcast
          acc[r] += w.x*alo.x + w.y*alo.y + w.z*ahi.x + w.w*ahi.y;
        }
      }
      #pragma unroll
      for (int r = 0; r < 8; ++r) sm.redA[wv][r][b] = acc[r];
      __syncthreads();

      if (tid < 128) {
        const int jj = tid >> 6;
        const int j  = j0 + jj;
        float gs[4];
        #pragma unroll
        for (int g = 0; g < 4; ++g)
          gs[g] = sm.redA[0][g*2+jj][b] + sm.redA[1][g*2+jj][b]
                + sm.redA[2][g*2+jj][b] + sm.redA[3][g*2+jj][b] + bsum[g];
        float cn = sigm(gs[1])*c_reg + sigm(gs[0])*tanhf(gs[2]);
        c_reg = cn;
        float hn = sigm(gs[3])*tanhf(cn);
        cstore1(hW + (j>>2)*256 + b*4 + (j&3), hn);
      }
    }
    gridbar(p.bar, ++bk);

    // ============ Phase B: iface GEMM (+ transpose x_{t+1}) ============
    {
      if (bi < 57) {
        float accB[8];
        #pragma unroll
        for (int r = 0; r < 8; ++r) accB[r] = 0.f;
        #pragma unroll 4
        for (int kk = 0; kk < 32; ++kk) {
          const float* h8 = hW + (((((wv<<5)+kk) << 6) + b) << 2);
          float2 alo = cload2(h8);
          float2 ahi = cload2(h8 + 2);
          #pragma unroll
          for (int r = 0; r < 8; ++r) {
            float4 w = *(const float4*)(wbB[r] + kk*4);
            accB[r] += w.x*alo.x + w.y*alo.y + w.z*ahi.x + w.w*ahi.y;
          }
        }
        #pragma unroll
        for (int r = 0; r < 8; ++r) sm.redA[wv][r][b] = accB[r];
        __syncthreads();
        {
          const int r0 = tid >> 6;
          #pragma unroll
          for (int half = 0; half < 2; ++half) {
            const int r = r0 + half*4;
            const int o = bi*8 + r;
            if (o < 453) {
              float s = sm.redA[0][r][b] + sm.redA[1][r][b]
                      + sm.redA[2][r][b] + sm.redA[3][r][b] + bintB[half];
              cstore1(p.ifc + (size_t)b*IFLD + o, s);
            }
          }
        }
      }
      if (bi >= 240 && t+1 < TT_) {
        const int g  = (bi - 240)*NTHR + tid;
        const int bb = g >> 6, kq = g & 63;
        float4 v = *(const float4*)(p.x + (size_t)bb*(TT_*DIN_)
                                    + (size_t)(t+1)*DIN_ + 4*kq);
        float* d = p.xbuf + nxt*16384 + kq*256 + bb*4;
        cstore2(d,   make_float2(v.x, v.y));
        cstore2(d+2, make_float2(v.z, v.w));
      }
    }
    gridbar(p.bar, ++bk);

    // ========= Phase C: content addressing (lane = memory slot) =========
    if (bi < BB_) {
      const int bb = bi;
      const int n  = tid & 127;
      const int wh = tid >> 7;

      // 1) stage ifc row
      for (int i = tid; i < 228; i += NTHR) {
        float2 v = cload2(p.ifc + (size_t)bb*IFLD + 2*i);
        sm.c.ifcS[2*i]   = v.x;
        sm.c.ifcS[2*i+1] = v.y;
      }
      __syncthreads();

      // 2) key pack + key norms (wave 0)
      if (tid < 64) {
        const int w = tid;
        float wk = sm.c.ifcS[260+w];
        float r0 = sm.c.ifcS[w],      r1 = sm.c.ifcS[64+w];
        float r2 = sm.c.ifcS[128+w],  r3 = sm.c.ifcS[192+w];
        float er  = sigm(sm.c.ifcS[325+w]);
        float wvc = sm.c.ifcS[389+w];
        sm.c.kpk[w][0]=wk; sm.c.kpk[w][1]=r0; sm.c.kpk[w][2]=r1; sm.c.kpk[w][3]=r2;
        sm.c.kpk[w][4]=r3; sm.c.kpk[w][5]=er; sm.c.kpk[w][6]=wvc; sm.c.kpk[w][7]=0.f;
        float s0 = wredsum(wk*wk);
        float s1 = wredsum(r0*r0);
        float s2 = wredsum(r1*r1);
        float s3 = wredsum(r2*r2);
        float s4 = wredsum(r3*r3);
        if (w == 0) {
          sm.c.scal[0] = fmaxf(sqrtf(s0), EPSV);
          sm.c.scal[1] = fmaxf(sqrtf(s1), EPSV);
          sm.c.scal[2] = fmaxf(sqrtf(s2), EPSV);
          sm.c.scal[3] = fmaxf(sqrtf(s3), EPSV);
          sm.c.scal[4] = fmaxf(sqrtf(s4), EPSV);
        }
      }
      __syncthreads();

      // 3) pass1: write-key dot + pre-update norm (w-serial, half per thread)
      {
        float dotw = 0.f, q = 0.f;
        const int w0 = wh*32;
        #pragma unroll 8
        for (int w = w0; w < w0+32; ++w) {
          float m = memS[n][w];
          dotw += sm.c.kpk[w][0]*m;
          q    += m*m;
        }
        sm.c.dH[wh][n] = dotw;
        sm.c.qH[wh][n] = q;
      }
      __syncthreads();

      // 4) write softmax over 128 slots (one value per thread, 2 waves)
      float a_n = 0.f, e_n = 0.f;
      const float wstr = softp(sm.c.ifcS[324]) + 1.f;
      if (tid < 128) {
        float dot = sm.c.dH[0][n] + sm.c.dH[1][n];
        float q2  = sm.c.qH[0][n] + sm.c.qH[1][n];
        a_n = wstr * dot / (sm.c.scal[0] * fmaxf(sqrtf(q2), EPSV));
        float mx = wredmax(a_n);
        if ((tid & 63) == 0) sm.c.red2[tid>>6] = mx;
      }
      __syncthreads();
      if (tid < 128) {
        float mx = fmaxf(sm.c.red2[0], sm.c.red2[1]);
        e_n = expf(a_n - mx);
        float s = wredsum(e_n);
        if ((tid & 63) == 0) sm.c.red2[4 + (tid>>6)] = s;
      }
      __syncthreads();
      if (tid < 128)
        sm.c.wwS[n] = e_n / (sm.c.red2[4] + sm.c.red2[5]);
      __syncthreads();

      // 5) pass2: memory update + read-key dots + post norm
      {
        float ww_n = sm.c.wwS[n];
        float nrm=0.f, d0=0.f, d1=0.f, d2=0.f, d3=0.f;
        const int w0 = wh*32;
        #pragma unroll 4
        for (int w = w0; w < w0+32; ++w) {
          float4 k0 = *(const float4*)&sm.c.kpk[w][0];
          float4 k1 = *(const float4*)&sm.c.kpk[w][4];
          float m  = memS[n][w];
          float mn = m*(1.f - ww_n*k1.y) + ww_n*k1.z;
          memS[n][w] = mn;
          nrm += mn*mn;
          d0 += k0.y*mn; d1 += k0.z*mn; d2 += k0.w*mn; d3 += k1.x*mn;
        }
        sm.c.nH[wh][n] = nrm;
        sm.c.drH[wh][0][n]=d0; sm.c.drH[wh][1][n]=d1;
        sm.c.drH[wh][2][n]=d2; sm.c.drH[wh][3][n]=d3;
      }
      __syncthreads();

      // 6) read scores
      if (tid < 128) {
        float nrm = sm.c.nH[0][n] + sm.c.nH[1][n];
        float inm = 1.f / fmaxf(sqrtf(nrm), EPSV);
        #pragma unroll
        for (int r = 0; r < RR_; ++r) {
          float rstr = softp(sm.c.ifcS[256+r]) + 1.f;
          float dr = sm.c.drH[0][r][n] + sm.c.drH[1][r][n];
          sm.c.rwS[r][n] = rstr * dr * inm / sm.c.scal[1+r];
        }
      }
      __syncthreads();

      // 7) read softmaxes: wave wv = head wv
      {
        float v0 = sm.c.rwS[wv][b], v1 = sm.c.rwS[wv][b+64];
        float mx = wredmax(fmaxf(v0, v1));
        float e0 = expf(v0-mx), e1 = expf(v1-mx);
        float s  = wredsum(e0+e1);
        sm.c.rwS[wv][b]    = e0/s;
        sm.c.rwS[wv][b+64] = e1/s;
      }
      __syncthreads();

      // 8) rv[r][w] = sum_n rw[r][n] * mem[n][w]
      {
        float acc = 0.f;
        #pragma unroll 8
        for (int n2 = 0; n2 < NMEM_; n2 += 4) {
          float4 r4 = *(const float4*)&sm.c.rwS[wv][n2];
          acc += r4.x*memS[n2][b]   + r4.y*memS[n2+1][b]
               + r4.z*memS[n2+2][b] + r4.w*memS[n2+3][b];
        }
        const int k = wv*64 + b;
        cstore1(p.rvp + (k>>2)*256 + bb*4 + (k&3), acc);
      }
    }
    gridbar(p.bar, ++bk);
  }

  // ================= Output projection (last step only) =================
  if (bi < 64) {
    const int o0 = bi*4;
    float acc[4] = {0.f, 0.f, 0.f, 0.f};
    #pragma unroll 4
    for (int kk = 0; kk < 48; ++kk) {
      const int k = wv*192 + kk*4;
      const float* a8 = (k < 512)
        ? (p.hp  + ((((k    )>>2) << 6) + b)*4)     // final h lives in hp[0]
        : (p.rvp + ((((k-512)>>2) << 6) + b)*4);
      float2 alo = cload2(a8);
      float2 ahi = cload2(a8 + 2);
      #pragma unroll
      for (int r = 0; r < 4; ++r) {
        float4 w = *(const float4*)(p.Wout + (size_t)(o0+r)*(HH_ + RR_*WWID_) + k);
        acc[r] += w.x*alo.x + w.y*alo.y + w.z*ahi.x + w.w*ahi.y;
      }
    }
    #pragma unroll
    for (int r = 0; r < 4; ++r) sm.redO[wv][r][b] = acc[r];
    __syncthreads();
    if (tid < 64) {
      float4 o4;
      float* po = (float*)&o4;
      #pragma unroll
      for (int r = 0; r < 4; ++r)
        po[r] = sm.redO[0][r][b] + sm.redO[1][r][b] + sm.redO[2][r][b]
              + sm.redO[3][r][b] + p.bout[o0+r];
      *(float4*)(p.out + (size_t)b*DOUT_ + o0) = o4;
    }
  }
}

extern "C" void kernel_launch(void* const* d_in, const int* in_sizes, int n_in,
                              void* d_out, int out_size, void* d_ws, size_t ws_size,
                              hipStream_t stream)
{
  Params prm;
  prm.x    = (const float*)d_in[0];
  prm.Wih  = (const float*)d_in[1];
  prm.Whh  = (const float*)d_in[2];
  prm.bih  = (const float*)d_in[3];
  prm.bhh  = (const float*)d_in[4];
  prm.Wint = (const float*)d_in[5];
  prm.bint = (const float*)d_in[6];
  prm.Wout = (const float*)d_in[7];
  prm.bout = (const float*)d_in[8];
  prm.out  = (float*)d_out;

  float* ws = (float*)d_ws;
  size_t off = 0;
  prm.xbuf = ws + off; off += 2*16384;
  prm.hp   = ws + off; off += 2*32768;
  prm.rvp  = ws + off; off += 16384;
  prm.ifc  = ws + off; off += 64*IFLD;
  prm.bar  = (unsigned*)(ws + off); off += 512;

  k_initbar<<<1, 512, 0, stream>>>(prm.bar);
  k_persist<<<NBLK, NTHR, 0, stream>>>(prm);
}